// Round 13
// baseline (4896.119 us; speedup 1.0000x reference)
//
#include <hip/hip_runtime.h>
#include <math.h>

typedef __attribute__((ext_vector_type(8))) short short8;
typedef __attribute__((ext_vector_type(4))) float floatx4;
typedef __attribute__((ext_vector_type(4))) unsigned uintx4;

#define NB 256
#define NH 512
#define NXP 256
#define NT 512
#define GHP 100

#define MFMA __builtin_amdgcn_mfma_f32_16x16x32_bf16

__device__ __forceinline__ unsigned short f2bf(float f) {
    union { float f; unsigned u; } x; x.f = f;
    unsigned r = x.u + 0x7FFFu + ((x.u >> 16) & 1u);
    return (unsigned short)(r >> 16);
}
__device__ __forceinline__ float sigmoidf_(float x) { return 1.0f / (1.0f + __expf(-x)); }
__device__ __forceinline__ float tanhf_(float x) {
    float e = __expf(2.f * x);
    return 1.f - 2.f / (e + 1.f);
}

__device__ __forceinline__ short8 cvt8(float4 u, float4 v) {
    short8 r;
    r[0] = (short)f2bf(u.x); r[1] = (short)f2bf(u.y);
    r[2] = (short)f2bf(u.z); r[3] = (short)f2bf(u.w);
    r[4] = (short)f2bf(v.x); r[5] = (short)f2bf(v.y);
    r[6] = (short)f2bf(v.z); r[7] = (short)f2bf(v.w);
    return r;
}

// ---- device-coherent data ops (sc0 sc1) — PROVEN cross-XCD (r3/r5/r7).
//      sc0-only REFUTED (r6). tagged-data REFUTED (r10).
__device__ __forceinline__ void ldg4_c(const void* p0, const void* p1,
                                       const void* p2, const void* p3,
                                       uintx4& r0, uintx4& r1, uintx4& r2, uintx4& r3) {
    asm volatile(
        "global_load_dwordx4 %0, %4, off sc0 sc1\n\t"
        "global_load_dwordx4 %1, %5, off sc0 sc1\n\t"
        "global_load_dwordx4 %2, %6, off sc0 sc1\n\t"
        "global_load_dwordx4 %3, %7, off sc0 sc1\n\t"
        "s_waitcnt vmcnt(0)"
        : "=&v"(r0), "=&v"(r1), "=&v"(r2), "=&v"(r3)
        : "v"(p0), "v"(p1), "v"(p2), "v"(p3) : "memory");
}
__device__ __forceinline__ void st32_c(void* p, unsigned v) {
    asm volatile("global_store_dword %0, %1, off sc0 sc1" :: "v"(p), "v"(v) : "memory");
}
__device__ __forceinline__ void vm_drain() {
    asm volatile("s_waitcnt vmcnt(0)" ::: "memory");
}

// ---- flag fabric: relaxed agent atomics (proven), single writer,
//      one flag per 64B line: flag i at f[i*16]. ----
__device__ __forceinline__ void flag_set(int* f, int v) {
    __hip_atomic_store(f, v, __ATOMIC_RELAXED, __HIP_MEMORY_SCOPE_AGENT);
}
__device__ __forceinline__ void poll16(const int* f, int target, int lane) {
    const int* fp = f + (lane & 15) * 16;
    for (;;) {
        int v = __hip_atomic_load(fp, __ATOMIC_RELAXED, __HIP_MEMORY_SCOPE_AGENT);
        if (__ballot(v < target) == 0ull) break;
        __builtin_amdgcn_s_sleep(1);
    }
}

__global__ void k_cvt(const float* __restrict__ src, unsigned short* __restrict__ dst, int n) {
    int i = blockIdx.x * blockDim.x + threadIdx.x;
    int stride = gridDim.x * blockDim.x;
    for (; i < n; i += stride) dst[i] = f2bf(src[i]);
}

struct KParams {
    const float *xl, *xt, *xw, *xs;
    const float *bih, *bhh, *bt;
    const unsigned short *Wihb, *Whhb, *Wthb, *Wtxb;
    unsigned short *hb0, *hb1;
    float *out;
    int *flags;
};

// ONE-EXCHANGE structure: every block computes ALL 256 x' cols for its 16 rows
// (x' weights register-resident, 336 VGPR), x' lives only in LDS. Only h is
// exchanged (1 broadcast/step). Whh slice streamed from L2 in the gh loop.
__global__ __launch_bounds__(256, 1)
void k_persist(KParams P)
{
    const int tid   = threadIdx.x;
    const int w     = tid >> 6;
    const int lane  = tid & 63;
    const int lr    = lane & 15;
    const int lkrow = lane >> 4;
    const int lk    = lkrow * 8;
    const int bid   = blockIdx.x;
    const int grp   = bid >> 4;
    const int jc    = bid & 15;
    const int m0    = grp * 16;
    const int j0    = jc * 32;
    const int xb    = w * 64;           // this wave's x' col base (4 tiles)

    int* hfl = P.flags + grp * 512;     // 16 h flags, one per 64B line

    __shared__ unsigned short sh_h[16 * 512];
    __shared__ unsigned short sh_xp[16 * 256];
    __shared__ float sh_gh[16 * GHP];
    __shared__ float sh_gx[2][16 * GHP];
    __shared__ float sh_b[6][32];
    __shared__ float sh_bt[256];

    if (tid < 32) {
        sh_b[0][tid] = P.bih[j0 + tid];
        sh_b[1][tid] = P.bih[512 + j0 + tid];
        sh_b[2][tid] = P.bih[1024 + j0 + tid];
        sh_b[3][tid] = P.bhh[j0 + tid];
        sh_b[4][tid] = P.bhh[512 + j0 + tid];
        sh_b[5][tid] = P.bhh[1024 + j0 + tid];
    }
    sh_bt[tid] = P.bt[tid];

    float hold0 = 0.f, hold1 = 0.f;     // h_old registers (r12)

    // ---- step-invariant weights in registers ----
    short8 bWt[4][16];     // Wth: 4 x' tiles (cols xb+tl*16+lr), K=512  (256 VGPR)
    short8 bWtx[4][5];     // Wtx: same tiles, K=160                     (80 VGPR)
    short8 bWih[3][4];     // gx units (r7 shape)                        (48 VGPR)
    #pragma unroll
    for (int tl = 0; tl < 4; ++tl) {
        const unsigned short* bp = P.Wthb + (size_t)(xb + tl * 16 + lr) * NH + lk;
        #pragma unroll
        for (int kb = 0; kb < 16; ++kb) bWt[tl][kb] = *(const short8*)(bp + kb * 32);
        const unsigned short* bx = P.Wtxb + (size_t)(xb + tl * 16 + lr) * 160 + lk;
        #pragma unroll
        for (int c = 0; c < 5; ++c) bWtx[tl][c] = *(const short8*)(bx + c * 32);
    }
    #pragma unroll
    for (int i = 0; i < 3; ++i) {
        const int u = w * 3 + i, tile = u >> 1, kh = u & 1;
        const int g = tile >> 1, sub = tile & 1;
        const unsigned short* bp =
            P.Wihb + (size_t)(g * 512 + j0 + sub * 16 + lr) * NXP + kh * 128 + lk;
        #pragma unroll
        for (int kb = 0; kb < 4; ++kb) bWih[i][kb] = *(const short8*)(bp + kb * 32);
    }
    // Whh stream pointers (waves 0-2: gate w, cols j0..j0+31 as 2 tiles)
    const unsigned short* whh0 = P.Whhb + (size_t)(w * 512 + j0 + lr) * NH + lk;
    const unsigned short* whh1 = P.Whhb + (size_t)(w * 512 + j0 + 16 + lr) * NH + lk;
    __syncthreads();

    for (int t = 0; t < NT; ++t) {
        const unsigned short* hsrc = (t & 1) ? P.hb1 : P.hb0;
        unsigned short*       hdst = (t & 1) ? P.hb0 : P.hb1;

        // ---- x-part of x' BEFORE the poll (hidden under the flag wait) ----
        floatx4 axp[4];
        axp[0] = (floatx4){0.f,0.f,0.f,0.f}; axp[1] = (floatx4){0.f,0.f,0.f,0.f};
        axp[2] = (floatx4){0.f,0.f,0.f,0.f}; axp[3] = (floatx4){0.f,0.f,0.f,0.f};
        {
            const size_t r = (size_t)(m0 + lr);
            // half 1: c = 0,1,2
            {
                float4 q[3][2];
                #pragma unroll
                for (int c = 0; c < 3; ++c) {
                    const float* pa = (c < 2) ? P.xl + (r * NT + t) * 64 + c * 32 + lk
                                              : P.xt + (r * NT + t) * 32 + lk;
                    q[c][0] = *(const float4*)pa;
                    q[c][1] = *(const float4*)(pa + 4);
                }
                #pragma unroll
                for (int c = 0; c < 3; ++c) {
                    short8 a = cvt8(q[c][0], q[c][1]);
                    axp[0] = MFMA(a, bWtx[0][c], axp[0], 0, 0, 0);
                    axp[1] = MFMA(a, bWtx[1][c], axp[1], 0, 0, 0);
                    axp[2] = MFMA(a, bWtx[2][c], axp[2], 0, 0, 0);
                    axp[3] = MFMA(a, bWtx[3][c], axp[3], 0, 0, 0);
                }
            }
            // half 2: c = 3,4
            {
                float4 q[2][2];
                #pragma unroll
                for (int c = 0; c < 2; ++c) {
                    const float* pa = (c == 0) ? P.xw + (r * NT + t) * 32 + lk
                                               : P.xs + (r * NT + t) * 32 + lk;
                    q[c][0] = *(const float4*)pa;
                    q[c][1] = *(const float4*)(pa + 4);
                }
                #pragma unroll
                for (int c = 0; c < 2; ++c) {
                    short8 a = cvt8(q[c][0], q[c][1]);
                    axp[0] = MFMA(a, bWtx[0][c + 3], axp[0], 0, 0, 0);
                    axp[1] = MFMA(a, bWtx[1][c + 3], axp[1], 0, 0, 0);
                    axp[2] = MFMA(a, bWtx[2][c + 3], axp[2], 0, 0, 0);
                    axp[3] = MFMA(a, bWtx[3][c + 3], axp[3], 0, 0, 0);
                }
            }
        }

        // ---- the ONE exchange: wait for h_t, stage h -> LDS ----
        poll16(hfl, t, lane);
        {
            const int row = tid & 15, c = (tid >> 4) * 32;   // r12 conflict-fixed
            const unsigned short* gp = hsrc + (size_t)(m0 + row) * NH + c;
            uintx4 r0, r1, r2, r3;
            ldg4_c(gp, gp + 8, gp + 16, gp + 24, r0, r1, r2, r3);
            const int sw = (row & 7) * 8;
            *(uintx4*)&sh_h[row * 512 + ((c +  0) ^ sw)] = r0;
            *(uintx4*)&sh_h[row * 512 + ((c +  8) ^ sw)] = r1;
            *(uintx4*)&sh_h[row * 512 + ((c + 16) ^ sw)] = r2;
            *(uintx4*)&sh_h[row * 512 + ((c + 24) ^ sw)] = r3;
        }
        __syncthreads();

        // ---- x' h-part: 4 tiles, A read once per K-chunk ----
        {
            const int sw = (lr & 7) * 8;
            #pragma unroll
            for (int kb = 0; kb < 16; ++kb) {
                short8 a = *(const short8*)&sh_h[lr * 512 + ((kb * 32 + lk) ^ sw)];
                axp[0] = MFMA(a, bWt[0][kb], axp[0], 0, 0, 0);
                axp[1] = MFMA(a, bWt[1][kb], axp[1], 0, 0, 0);
                axp[2] = MFMA(a, bWt[2][kb], axp[2], 0, 0, 0);
                axp[3] = MFMA(a, bWt[3][kb], axp[3], 0, 0, 0);
            }
        }
        // write x' -> LDS (C-layout col=lr, row=lkrow*4+rg; swizzled for gx reads)
        #pragma unroll
        for (int tl = 0; tl < 4; ++tl) {
            #pragma unroll
            for (int rg = 0; rg < 4; ++rg) {
                const int m = lkrow * 4 + rg;
                const int n = xb + tl * 16 + lr;
                sh_xp[m * 256 + (n ^ ((m & 7) * 8))] =
                    f2bf(tanhf_(axp[tl][rg] + sh_bt[n]));
            }
        }

        // ---- gh (waves 0-2): B streamed from L2 (Whh slice, L2-hot) ----
        if (w < 3) {
            floatx4 a0 = (floatx4){0.f,0.f,0.f,0.f};
            floatx4 a1 = (floatx4){0.f,0.f,0.f,0.f};
            const int sw = (lr & 7) * 8;
            #pragma unroll
            for (int kb = 0; kb < 16; ++kb) {
                short8 a  = *(const short8*)&sh_h[lr * 512 + ((kb * 32 + lk) ^ sw)];
                short8 b0 = *(const short8*)(whh0 + kb * 32);
                short8 b1 = *(const short8*)(whh1 + kb * 32);
                a0 = MFMA(a, b0, a0, 0, 0, 0);
                a1 = MFMA(a, b1, a1, 0, 0, 0);
            }
            #pragma unroll
            for (int rg = 0; rg < 4; ++rg) {
                const int row = lkrow * 4 + rg;
                sh_gh[row * GHP + w * 32 + lr]      = a0[rg];
                sh_gh[row * GHP + w * 32 + 16 + lr] = a1[rg];
            }
        }
        __syncthreads();

        // ---- gx: 3 K-split units/wave from sh_xp (r7 shape) ----
        #pragma unroll
        for (int i = 0; i < 3; ++i) {
            const int u = w * 3 + i, tile = u >> 1, kh = u & 1;
            const int g = tile >> 1, sub = tile & 1;
            floatx4 acc = (floatx4){0.f,0.f,0.f,0.f};
            const int sw = (lr & 7) * 8;
            #pragma unroll
            for (int kb = 0; kb < 4; ++kb) {
                short8 a = *(const short8*)&sh_xp[lr * 256 + ((kh * 128 + kb * 32 + lk) ^ sw)];
                acc = MFMA(a, bWih[i][kb], acc, 0, 0, 0);
            }
            #pragma unroll
            for (int rg = 0; rg < 4; ++rg) {
                const int row = lkrow * 4 + rg;
                sh_gx[kh][row * GHP + g * 32 + sub * 16 + lr] = acc[rg];
            }
        }
        __syncthreads();

        // ---- epilogue: gates + h update (h_old in registers) ----
        {
            const int row = tid >> 4, jj = (tid & 15) * 2;
            float hn[2];
            #pragma unroll
            for (int jo = 0; jo < 2; ++jo) {
                const int j = jj + jo;
                float gxr = sh_gx[0][row * GHP + j]      + sh_gx[1][row * GHP + j];
                float gxz = sh_gx[0][row * GHP + 32 + j] + sh_gx[1][row * GHP + 32 + j];
                float gxn = sh_gx[0][row * GHP + 64 + j] + sh_gx[1][row * GHP + 64 + j];
                float ghr = sh_gh[row * GHP + j];
                float ghz = sh_gh[row * GHP + 32 + j];
                float ghn = sh_gh[row * GHP + 64 + j];
                float rg_ = sigmoidf_(gxr + ghr + sh_b[0][j] + sh_b[3][j]);
                float zg  = sigmoidf_(gxz + ghz + sh_b[1][j] + sh_b[4][j]);
                float ng  = tanhf_(gxn + sh_b[2][j] + rg_ * (ghn + sh_b[5][j]));
                float hold = jo ? hold1 : hold0;
                hn[jo] = (1.f - zg) * ng + zg * hold;
            }
            hold0 = hn[0]; hold1 = hn[1];
            unsigned d = (unsigned)f2bf(hn[0]) | ((unsigned)f2bf(hn[1]) << 16);
            st32_c(hdst + (size_t)(m0 + row) * NH + j0 + jj, d);
            if (t == NT - 1) {
                float2 o; o.x = hn[0]; o.y = hn[1];
                *(float2*)&P.out[(size_t)(m0 + row) * NH + j0 + jj] = o;
            }
            vm_drain();
        }
        __syncthreads();
        if (tid == 0) flag_set(hfl + jc * 16, t + 1);
    }
}

extern "C" void kernel_launch(void* const* d_in, const int* in_sizes, int n_in,
                              void* d_out, int out_size, void* d_ws, size_t ws_size,
                              hipStream_t stream)
{
    (void)in_sizes; (void)n_in; (void)out_size;
    const float* xl  = (const float*)d_in[0];
    const float* xt_ = (const float*)d_in[1];
    const float* xw  = (const float*)d_in[2];
    const float* xs  = (const float*)d_in[3];
    const float* Wih = (const float*)d_in[4];
    const float* Whh = (const float*)d_in[5];
    const float* bih = (const float*)d_in[6];
    const float* bhh = (const float*)d_in[7];
    const float* Wth = (const float*)d_in[8];
    const float* Wtx = (const float*)d_in[9];
    const float* bt  = (const float*)d_in[10];

    char* p = (char*)d_ws;
    int* flags = (int*)p;                       p += 32768;   // 16 groups x 2048 B
    unsigned short* hb0 = (unsigned short*)p;   p += (size_t)NB * NH * 2;
    unsigned short* hb1 = (unsigned short*)p;   p += (size_t)NB * NH * 2;
    unsigned short* Wihb = (unsigned short*)p;  p += (size_t)1536 * 256 * 2;
    unsigned short* Whhb = (unsigned short*)p;  p += (size_t)1536 * 512 * 2;
    unsigned short* Wthb = (unsigned short*)p;  p += (size_t)256 * 512 * 2;
    unsigned short* Wtxb = (unsigned short*)p;  p += (size_t)256 * 160 * 2;
    if ((size_t)(p - (char*)d_ws) > ws_size) return;

    k_cvt<<<256, 256, 0, stream>>>(Wih, Wihb, 1536 * 256);
    k_cvt<<<256, 256, 0, stream>>>(Whh, Whhb, 1536 * 512);
    k_cvt<<<64, 256, 0, stream>>>(Wth, Wthb, 256 * 512);
    k_cvt<<<32, 256, 0, stream>>>(Wtx, Wtxb, 256 * 160);
    hipMemsetAsync(flags, 0, 32768, stream);
    hipMemsetAsync(hb0, 0, (size_t)NB * NH * 2, stream);

    KParams P;
    P.xl = xl; P.xt = xt_; P.xw = xw; P.xs = xs;
    P.bih = bih; P.bhh = bhh; P.bt = bt;
    P.Wihb = Wihb; P.Whhb = Whhb; P.Wthb = Wthb; P.Wtxb = Wtxb;
    P.hb0 = hb0; P.hb1 = hb1;
    P.out = (float*)d_out; P.flags = flags;

    void* args[] = { &P };
    if (hipLaunchCooperativeKernel((const void*)k_persist, dim3(256), dim3(256),
                                   args, 0, stream) != hipSuccess) {
        k_persist<<<256, 256, 0, stream>>>(P);
    }
}

// Round 14
// 4036.982 us; speedup vs baseline: 1.2128x; 1.2128x over previous
//
#include <hip/hip_runtime.h>
#include <math.h>

typedef __attribute__((ext_vector_type(8))) short short8;
typedef __attribute__((ext_vector_type(4))) float floatx4;
typedef __attribute__((ext_vector_type(4))) unsigned uintx4;

#define NB 256
#define NH 512
#define NXP 256
#define NT 512
#define GHP 100

#define MFMA __builtin_amdgcn_mfma_f32_16x16x32_bf16

__device__ __forceinline__ unsigned short f2bf(float f) {
    union { float f; unsigned u; } x; x.f = f;
    unsigned r = x.u + 0x7FFFu + ((x.u >> 16) & 1u);
    return (unsigned short)(r >> 16);
}
__device__ __forceinline__ float sigmoidf_(float x) { return 1.0f / (1.0f + __expf(-x)); }

__device__ __forceinline__ short8 cvt8(float4 u, float4 v) {
    short8 r;
    r[0] = (short)f2bf(u.x); r[1] = (short)f2bf(u.y);
    r[2] = (short)f2bf(u.z); r[3] = (short)f2bf(u.w);
    r[4] = (short)f2bf(v.x); r[5] = (short)f2bf(v.y);
    r[6] = (short)f2bf(v.z); r[7] = (short)f2bf(v.w);
    return r;
}

// ---- device-coherent data ops (sc0 sc1) — PROVEN cross-XCD (r3/r5/r7).
//      sc0-only REFUTED (r6). h-tagged REFUTED (r10). >200 weight-VGPR REFUTED (r8/r13).
__device__ __forceinline__ void ldg4_c(const void* p0, const void* p1,
                                       const void* p2, const void* p3,
                                       uintx4& r0, uintx4& r1, uintx4& r2, uintx4& r3) {
    asm volatile(
        "global_load_dwordx4 %0, %4, off sc0 sc1\n\t"
        "global_load_dwordx4 %1, %5, off sc0 sc1\n\t"
        "global_load_dwordx4 %2, %6, off sc0 sc1\n\t"
        "global_load_dwordx4 %3, %7, off sc0 sc1\n\t"
        "s_waitcnt vmcnt(0)"
        : "=&v"(r0), "=&v"(r1), "=&v"(r2), "=&v"(r3)
        : "v"(p0), "v"(p1), "v"(p2), "v"(p3) : "memory");
}
__device__ __forceinline__ void ldg4_nw(const void* p, uintx4& r) {
    asm volatile("global_load_dwordx4 %0, %1, off sc0 sc1"
                 : "=&v"(r) : "v"(p) : "memory");
}
__device__ __forceinline__ void st32_c(void* p, unsigned v) {
    asm volatile("global_store_dword %0, %1, off sc0 sc1" :: "v"(p), "v"(v) : "memory");
}
__device__ __forceinline__ void vm_drain() {
    asm volatile("s_waitcnt vmcnt(0)" ::: "memory");
}

// ---- flag fabric (h only): relaxed agent atomics, single writer, 64B-spread ----
__device__ __forceinline__ void flag_set(int* f, int v) {
    __hip_atomic_store(f, v, __ATOMIC_RELAXED, __HIP_MEMORY_SCOPE_AGENT);
}
__device__ __forceinline__ void poll16(const int* f, int target, int lane) {
    const int* fp = f + (lane & 15) * 16;
    for (;;) {
        int v = __hip_atomic_load(fp, __ATOMIC_RELAXED, __HIP_MEMORY_SCOPE_AGENT);
        if (__ballot(v < target) == 0ull) break;
        __builtin_amdgcn_s_sleep(1);
    }
}

__global__ void k_cvt(const float* __restrict__ src, unsigned short* __restrict__ dst, int n) {
    int i = blockIdx.x * blockDim.x + threadIdx.x;
    int stride = gridDim.x * blockDim.x;
    for (; i < n; i += stride) dst[i] = f2bf(src[i]);
}

struct KParams {
    const float *xl, *xt, *xw, *xs;
    const float *bih, *bhh, *bt;
    const unsigned short *Wihb, *Whhb, *Wthb, *Wtxb;
    unsigned short *hb0, *hb1;
    unsigned *xT;            // tagged x': (epoch<<16)|bf16, one dword per element
    float *out;
    int *flags;
};

// r12 structure; x' exchange converted to tagged-data (2-RT chain: store -> poll
// detects data directly). h exchange unchanged (flag protocol).
__global__ __launch_bounds__(256, 1)
void k_persist(KParams P)
{
    const int tid   = threadIdx.x;
    const int w     = tid >> 6;
    const int lane  = tid & 63;
    const int lr    = lane & 15;
    const int lkrow = lane >> 4;
    const int lk    = lkrow * 8;
    const int bid   = blockIdx.x;
    const int grp   = bid >> 4;
    const int jc    = bid & 15;
    const int m0    = grp * 16;
    const int j0    = jc * 32;
    const int n0    = jc * 16;

    int* hfl = P.flags + grp * 512;

    __shared__ unsigned short sh_h[16 * 512];
    __shared__ unsigned short sh_xp[16 * 256];
    __shared__ float sh_gh[16 * GHP];
    __shared__ float sh_gx[2][16 * GHP];
    __shared__ float sh_b[6][32];
    __shared__ float sh_bt[16];

    if (tid < 32) {
        sh_b[0][tid] = P.bih[j0 + tid];
        sh_b[1][tid] = P.bih[512 + j0 + tid];
        sh_b[2][tid] = P.bih[1024 + j0 + tid];
        sh_b[3][tid] = P.bhh[j0 + tid];
        sh_b[4][tid] = P.bhh[512 + j0 + tid];
        sh_b[5][tid] = P.bhh[1024 + j0 + tid];
    }
    if (tid < 16) sh_bt[tid] = P.bt[n0 + tid];

    float hold0 = 0.f, hold1 = 0.f;    // h_old registers (r12)

    // ---- hoist step-invariant MFMA B-operands into registers (r7-proven) ----
    short8 bWih[3][4];
    short8 bWhh[2][16];
    #pragma unroll
    for (int i = 0; i < 3; ++i) {
        const int u = w * 3 + i, tile = u >> 1, kh = u & 1;
        const int g = tile >> 1, sub = tile & 1;
        const unsigned short* bp =
            P.Wihb + (size_t)(g * 512 + j0 + sub * 16 + lr) * NXP + kh * 128 + lk;
        #pragma unroll
        for (int kb = 0; kb < 4; ++kb) bWih[i][kb] = *(const short8*)(bp + kb * 32);
    }
    if (w < 3) {
        #pragma unroll
        for (int sub = 0; sub < 2; ++sub) {
            const unsigned short* bp =
                P.Whhb + (size_t)(w * 512 + j0 + sub * 16 + lr) * NH + lk;
            #pragma unroll
            for (int kb = 0; kb < 16; ++kb) bWhh[sub][kb] = *(const short8*)(bp + kb * 32);
        }
    } else {
        const unsigned short* bp = P.Wthb + (size_t)(n0 + lr) * NH + lk;
        #pragma unroll
        for (int kb = 0; kb < 16; ++kb) bWhh[0][kb] = *(const short8*)(bp + kb * 32);
        const unsigned short* bx = P.Wtxb + (size_t)(n0 + lr) * 160 + lk;
        #pragma unroll
        for (int c = 0; c < 5; ++c) bWhh[1][c] = *(const short8*)(bx + c * 32);
    }
    __syncthreads();

    for (int t = 0; t < NT; ++t) {
        const unsigned short* hsrc = (t & 1) ? P.hb1 : P.hb0;
        unsigned short*       hdst = (t & 1) ? P.hb0 : P.hb1;

        // x-input loads early (plain cached; overlaps the h-poll)
        float4 xq[5][2];
        if (w == 3) {
            const size_t r = (size_t)(m0 + lr);
            #pragma unroll
            for (int c = 0; c < 5; ++c) {
                const float* pa = (c < 2) ? P.xl + (r * NT + t) * 64 + c * 32 + lk
                                : (c == 2)? P.xt + (r * NT + t) * 32 + lk
                                : (c == 3)? P.xw + (r * NT + t) * 32 + lk
                                          : P.xs + (r * NT + t) * 32 + lk;
                xq[c][0] = *(const float4*)pa;
                xq[c][1] = *(const float4*)(pa + 4);
            }
        }

        // ---- h exchange (flag protocol, r12 conflict-fixed staging) ----
        poll16(hfl, t, lane);
        {
            const int row = tid & 15, c = (tid >> 4) * 32;
            const unsigned short* gp = hsrc + (size_t)(m0 + row) * NH + c;
            uintx4 r0, r1, r2, r3;
            ldg4_c(gp, gp + 8, gp + 16, gp + 24, r0, r1, r2, r3);
            const int sw = (row & 7) * 8;
            *(uintx4*)&sh_h[row * 512 + ((c +  0) ^ sw)] = r0;
            *(uintx4*)&sh_h[row * 512 + ((c +  8) ^ sw)] = r1;
            *(uintx4*)&sh_h[row * 512 + ((c + 16) ^ sw)] = r2;
            *(uintx4*)&sh_h[row * 512 + ((c + 24) ^ sw)] = r3;
        }
        __syncthreads();

        // ---- Phase A: gh (waves 0-2) / x' (wave 3, tagged fire-and-forget) ----
        if (w < 3) {
            floatx4 a0 = (floatx4){0.f,0.f,0.f,0.f};
            floatx4 a1 = (floatx4){0.f,0.f,0.f,0.f};
            const int sw = (lr & 7) * 8;
            #pragma unroll
            for (int kb = 0; kb < 16; ++kb) {
                short8 a = *(const short8*)&sh_h[lr * 512 + ((kb * 32 + lk) ^ sw)];
                a0 = MFMA(a, bWhh[0][kb], a0, 0, 0, 0);
                a1 = MFMA(a, bWhh[1][kb], a1, 0, 0, 0);
            }
            #pragma unroll
            for (int rg = 0; rg < 4; ++rg) {
                const int row = lkrow * 4 + rg;
                sh_gh[row * GHP + w * 32 + lr]      = a0[rg];
                sh_gh[row * GHP + w * 32 + 16 + lr] = a1[rg];
            }
        } else {
            floatx4 acc = (floatx4){0.f,0.f,0.f,0.f};
            const int sw = (lr & 7) * 8;
            #pragma unroll
            for (int kb = 0; kb < 16; ++kb) {
                short8 a = *(const short8*)&sh_h[lr * 512 + ((kb * 32 + lk) ^ sw)];
                acc = MFMA(a, bWhh[0][kb], acc, 0, 0, 0);
            }
            #pragma unroll
            for (int c = 0; c < 5; ++c) {
                short8 a = cvt8(xq[c][0], xq[c][1]);
                acc = MFMA(a, bWhh[1][c], acc, 0, 0, 0);
            }
            // tagged x' stores: no drain, no flag — the tag IS the readiness signal
            const unsigned xtag = ((unsigned)(t + 1)) << 16;
            #pragma unroll
            for (int rg = 0; rg < 4; ++rg) {
                const int row = lkrow * 4 + rg;
                unsigned short v = f2bf(tanhf(acc[rg] + sh_bt[lr]));
                st32_c(P.xT + (size_t)(m0 + row) * NXP + n0 + lr, xtag | (unsigned)v);
            }
        }

        // ---- x' exchange: poll the tagged data itself (2-RT chain) ----
        {
            const int row = tid & 15, c = (tid >> 4) * 16;      // 16 cols/thread
            const unsigned* bp = P.xT + (size_t)(m0 + row) * NXP + c;
            uintx4 B[4];
            unsigned pend = 0xFu;
            const unsigned tg = (unsigned)(t + 1);
            for (;;) {
                #pragma unroll
                for (int b = 0; b < 4; ++b)
                    if (pend & (1u << b)) ldg4_nw(bp + b * 4, B[b]);
                vm_drain();
                __builtin_amdgcn_sched_barrier(0);
                #pragma unroll
                for (int b = 0; b < 4; ++b)
                    if (pend & (1u << b)) {
                        if ((B[b][0] >> 16) == tg && (B[b][1] >> 16) == tg &&
                            (B[b][2] >> 16) == tg && (B[b][3] >> 16) == tg)
                            pend &= ~(1u << b);
                    }
                if (__ballot(pend != 0u) == 0ull) break;
                __builtin_amdgcn_s_sleep(1);
            }
            const int sw = (row & 7) * 8;
            #pragma unroll
            for (int q = 0; q < 2; ++q) {
                uintx4 pk;
                pk[0] = (B[2*q][0]   & 0xffffu) | (B[2*q][1]   << 16);
                pk[1] = (B[2*q][2]   & 0xffffu) | (B[2*q][3]   << 16);
                pk[2] = (B[2*q+1][0] & 0xffffu) | (B[2*q+1][1] << 16);
                pk[3] = (B[2*q+1][2] & 0xffffu) | (B[2*q+1][3] << 16);
                *(uintx4*)&sh_xp[row * 256 + ((c + 8 * q) ^ sw)] = pk;
            }
        }
        __syncthreads();

        // ---- Phase B: gx ----
        #pragma unroll
        for (int i = 0; i < 3; ++i) {
            const int u = w * 3 + i, tile = u >> 1, kh = u & 1;
            const int g = tile >> 1, sub = tile & 1;
            floatx4 acc = (floatx4){0.f,0.f,0.f,0.f};
            const int sw = (lr & 7) * 8;
            #pragma unroll
            for (int kb = 0; kb < 4; ++kb) {
                short8 a = *(const short8*)&sh_xp[lr * 256 + ((kh * 128 + kb * 32 + lk) ^ sw)];
                acc = MFMA(a, bWih[i][kb], acc, 0, 0, 0);
            }
            #pragma unroll
            for (int rg = 0; rg < 4; ++rg) {
                const int row = lkrow * 4 + rg;
                sh_gx[kh][row * GHP + g * 32 + sub * 16 + lr] = acc[rg];
            }
        }
        __syncthreads();

        // ---- epilogue: gates + h update (h_old in registers) ----
        {
            const int row = tid >> 4, jj = (tid & 15) * 2;
            float hn[2];
            #pragma unroll
            for (int jo = 0; jo < 2; ++jo) {
                const int j = jj + jo;
                float gxr = sh_gx[0][row * GHP + j]      + sh_gx[1][row * GHP + j];
                float gxz = sh_gx[0][row * GHP + 32 + j] + sh_gx[1][row * GHP + 32 + j];
                float gxn = sh_gx[0][row * GHP + 64 + j] + sh_gx[1][row * GHP + 64 + j];
                float ghr = sh_gh[row * GHP + j];
                float ghz = sh_gh[row * GHP + 32 + j];
                float ghn = sh_gh[row * GHP + 64 + j];
                float rg_ = sigmoidf_(gxr + ghr + sh_b[0][j] + sh_b[3][j]);
                float zg  = sigmoidf_(gxz + ghz + sh_b[1][j] + sh_b[4][j]);
                float ng  = tanhf(gxn + sh_b[2][j] + rg_ * (ghn + sh_b[5][j]));
                float hold = jo ? hold1 : hold0;
                hn[jo] = (1.f - zg) * ng + zg * hold;
            }
            hold0 = hn[0]; hold1 = hn[1];
            unsigned d = (unsigned)f2bf(hn[0]) | ((unsigned)f2bf(hn[1]) << 16);
            st32_c(hdst + (size_t)(m0 + row) * NH + j0 + jj, d);
            if (t == NT - 1) {
                float2 o; o.x = hn[0]; o.y = hn[1];
                *(float2*)&P.out[(size_t)(m0 + row) * NH + j0 + jj] = o;
            }
            vm_drain();
        }
        __syncthreads();
        if (tid == 0) flag_set(hfl + jc * 16, t + 1);
    }
}

extern "C" void kernel_launch(void* const* d_in, const int* in_sizes, int n_in,
                              void* d_out, int out_size, void* d_ws, size_t ws_size,
                              hipStream_t stream)
{
    (void)in_sizes; (void)n_in; (void)out_size;
    const float* xl  = (const float*)d_in[0];
    const float* xt_ = (const float*)d_in[1];
    const float* xw  = (const float*)d_in[2];
    const float* xs  = (const float*)d_in[3];
    const float* Wih = (const float*)d_in[4];
    const float* Whh = (const float*)d_in[5];
    const float* bih = (const float*)d_in[6];
    const float* bhh = (const float*)d_in[7];
    const float* Wth = (const float*)d_in[8];
    const float* Wtx = (const float*)d_in[9];
    const float* bt  = (const float*)d_in[10];

    char* p = (char*)d_ws;
    int* flags = (int*)p;                       p += 32768;
    unsigned* xT = (unsigned*)p;                p += (size_t)NB * NXP * 4;
    unsigned short* hb0 = (unsigned short*)p;   p += (size_t)NB * NH * 2;
    unsigned short* hb1 = (unsigned short*)p;   p += (size_t)NB * NH * 2;
    unsigned short* Wihb = (unsigned short*)p;  p += (size_t)1536 * 256 * 2;
    unsigned short* Whhb = (unsigned short*)p;  p += (size_t)1536 * 512 * 2;
    unsigned short* Wthb = (unsigned short*)p;  p += (size_t)256 * 512 * 2;
    unsigned short* Wtxb = (unsigned short*)p;  p += (size_t)256 * 160 * 2;
    if ((size_t)(p - (char*)d_ws) > ws_size) return;

    k_cvt<<<256, 256, 0, stream>>>(Wih, Wihb, 1536 * 256);
    k_cvt<<<256, 256, 0, stream>>>(Whh, Whhb, 1536 * 512);
    k_cvt<<<64, 256, 0, stream>>>(Wth, Wthb, 256 * 512);
    k_cvt<<<32, 256, 0, stream>>>(Wtx, Wtxb, 256 * 160);
    hipMemsetAsync(flags, 0, 32768, stream);
    // CRITICAL for graph replay: stale tags from a prior replay would falsely
    // satisfy epoch checks with old data — clear every launch.
    hipMemsetAsync(xT, 0, (size_t)NB * NXP * 4, stream);
    hipMemsetAsync(hb0, 0, (size_t)NB * NH * 2, stream);

    KParams P;
    P.xl = xl; P.xt = xt_; P.xw = xw; P.xs = xs;
    P.bih = bih; P.bhh = bhh; P.bt = bt;
    P.Wihb = Wihb; P.Whhb = Whhb; P.Wthb = Wthb; P.Wtxb = Wtxb;
    P.hb0 = hb0; P.hb1 = hb1; P.xT = xT;
    P.out = (float*)d_out; P.flags = flags;

    void* args[] = { &P };
    if (hipLaunchCooperativeKernel((const void*)k_persist, dim3(256), dim3(256),
                                   args, 0, stream) != hipSuccess) {
        k_persist<<<256, 256, 0, stream>>>(P);
    }
}